// Round 2
// baseline (221.001 us; speedup 1.0000x reference)
//
#include <hip/hip_runtime.h>
#include <math.h>

#define NQ 6
#define NL 3
#define DIM 64

// ---------- compile-time CNOT-ring permutation tables ----------
// CNOT(ctrl,tgt): new[k] = old[k ^ tb] when ctrl bit of k set (ctrl bit unchanged).
constexpr int cnot_map(int k, int ctrl, int tgt) {
    const int cb = 1 << (5 - ctrl), tb = 1 << (5 - tgt);
    return (k & cb) ? (k ^ tb) : k;
}
// Full ring applied to state s: s' = C(5,0) C(4,5) C(3,4) C(2,3) C(1,2) C(0,1) s
// => s'[k] = s[c01(c12(c23(c34(c45(c50(k))))))]
constexpr int ring_map(int k) {
    k = cnot_map(k, 5, 0);
    k = cnot_map(k, 4, 5);
    k = cnot_map(k, 3, 4);
    k = cnot_map(k, 2, 3);
    k = cnot_map(k, 1, 2);
    k = cnot_map(k, 0, 1);
    return k;
}
struct Perms { int p[NL + 1][DIM]; };
constexpr Perms make_perms() {
    Perms P{};
    for (int k = 0; k < DIM; k++) P.p[0][k] = k;
    // logical index k at layer l+1 lives at physical slot p[l][ring_map(k)]
    for (int l = 0; l < NL; l++)
        for (int k = 0; k < DIM; k++)
            P.p[l + 1][k] = P.p[l][ring_map(k)];
    return P;
}
constexpr Perms PP = make_perms();

__global__ __launch_bounds__(256, 1)  // 1 wave/EU min => 512-VGPR budget, no spills
void qsim_kernel(const float* __restrict__ x, const float* __restrict__ w,
                 float* __restrict__ out, int B) {
    const int b = blockIdx.x * blockDim.x + threadIdx.x;
    if (b >= B) return;

    // ---- load x[b][0..5] via 3x float2 ----
    const float2* x2 = (const float2*)x;
    float2 v0 = x2[b * 3 + 0];
    float2 v1 = x2[b * 3 + 1];
    float2 v2 = x2[b * 3 + 2];
    float xi[NQ] = {v0.x, v0.y, v1.x, v1.y, v2.x, v2.y};

    // ---- per-sample RY angles: phi = (pi/2)*tanh(x); fast tanh via exp ----
    float C[NQ], S[NQ];
#pragma unroll
    for (int i = 0; i < NQ; i++) {
        float e = __expf(2.0f * xi[i]);                       // e^{2x}
        float t = 1.0f - 2.0f * __builtin_amdgcn_rcpf(e + 1.0f); // tanh(x)
        float ph = 1.5707963267948966f * t;
        __sincosf(ph, &S[i], &C[i]);
    }

    // ---- state in registers: |0...0> ----
    float sr[DIM], si[DIM];
#pragma unroll
    for (int k = 0; k < DIM; k++) { sr[k] = 0.0f; si[k] = 0.0f; }
    sr[0] = 1.0f;

#pragma unroll
    for (int layer = 0; layer < NL; layer++) {
#pragma unroll
        for (int q = 0; q < NQ; q++) {
            // M = RZ(a2) @ RY(a1) @ RZ(a0)  (wave-uniform; w loads scalarize)
            const float a0 = w[(layer * NQ + q) * 3 + 0];
            const float a1 = w[(layer * NQ + q) * 3 + 1];
            const float a2 = w[(layer * NQ + q) * 3 + 2];
            float ch, sh, cp, sp, cm, sm;
            __sincosf(0.5f * a1, &sh, &ch);
            __sincosf(0.5f * (a0 + a2), &sp, &cp);
            __sincosf(0.5f * (a0 - a2), &sm, &cm);
            const float m00r =  ch * cp, m00i = -ch * sp;
            const float m01r = -sh * cm, m01i = -sh * sm;
            const float m10r =  sh * cm, m10i = -sh * sm;
            const float m11r =  ch * cp, m11i =  ch * sp;
            // G = M @ RY(phi_q): per-thread fused gate
            const float c = C[q], s = S[q];
            const float g00r =  m00r * c + m01r * s, g00i =  m00i * c + m01i * s;
            const float g01r = -m00r * s + m01r * c, g01i = -m00i * s + m01i * c;
            const float g10r =  m10r * c + m11r * s, g10i =  m10i * c + m11i * s;
            const float g11r = -m10r * s + m11r * c, g11i = -m10i * s + m11i * c;

            // apply on wire q through the layer's compile-time permutation
            const int right = 1 << (5 - q);
            const int left  = 1 << q;
#pragma unroll
            for (int l = 0; l < left; l++) {
#pragma unroll
                for (int r = 0; r < right; r++) {
                    const int i0l = (l * 2) * right + r;     // logical pair indices
                    const int i1l = i0l + right;
                    const int i0 = PP.p[layer][i0l];          // physical register slots
                    const int i1 = PP.p[layer][i1l];
                    const float ar = sr[i0], ai = si[i0];
                    const float br = sr[i1], bi = si[i1];
                    sr[i0] = g00r * ar - g00i * ai + g01r * br - g01i * bi;
                    si[i0] = g00r * ai + g00i * ar + g01r * bi + g01i * br;
                    sr[i1] = g10r * ar - g10i * ai + g11r * br - g11i * bi;
                    si[i1] = g10r * ai + g10i * ar + g11r * bi + g11i * br;
                }
            }
        }
        // CNOT ring: zero instructions — absorbed into PP.p[layer+1]
    }

    // ---- expvals: out[q] = sum_k sign_q(k) * |amp at PP.p[NL][k]|^2 ----
    float acc[NQ] = {0.f, 0.f, 0.f, 0.f, 0.f, 0.f};
#pragma unroll
    for (int k = 0; k < DIM; k++) {
        const int j = PP.p[NL][k];
        const float p = sr[j] * sr[j] + si[j] * si[j];
#pragma unroll
        for (int q = 0; q < NQ; q++) {
            if (k & (1 << (5 - q))) acc[q] -= p; else acc[q] += p;
        }
    }
    float2* o2 = (float2*)out;
    o2[b * 3 + 0] = make_float2(acc[0], acc[1]);
    o2[b * 3 + 1] = make_float2(acc[2], acc[3]);
    o2[b * 3 + 2] = make_float2(acc[4], acc[5]);
}

extern "C" void kernel_launch(void* const* d_in, const int* in_sizes, int n_in,
                              void* d_out, int out_size, void* d_ws, size_t ws_size,
                              hipStream_t stream) {
    const float* x = (const float*)d_in[0];
    const float* w = (const float*)d_in[1];
    float* out = (float*)d_out;
    const int B = in_sizes[0] / NQ;
    const int block = 256;
    const int grid = (B + block - 1) / block;
    qsim_kernel<<<grid, block, 0, stream>>>(x, w, out, B);
}